// Round 2
// baseline (275.952 us; speedup 1.0000x reference)
//
#include <hip/hip_runtime.h>
#include <hip/hip_bf16.h>

#define L_LEN 16384
#define C_CH  256
#define H_HEADS 16
#define W_WIN 15

typedef __attribute__((ext_vector_type(8))) short bf16x8;
typedef __attribute__((ext_vector_type(4))) float f32x4;
typedef unsigned short ushort_t;

// ---------------- ws layout (bytes) ----------------
// Ag    : [256][4096] bf16  @ 0      (2 MB)
// xb    : [16384][256] bf16 @ 2 MB   (8 MB)
// scfoc : [16][16384] f32   @ 10 MB  (1 MB)   scores (atomic) -> focus (in-place)
// bias  : [256] f32         @ 11 MB  (1 KB)
// total 11 MB + 1 KB  (kept < out_size = 16 MB to be safe vs ws_size)

__device__ __forceinline__ void gll16(const void* g, void* l) {
    __builtin_amdgcn_global_load_lds(
        (const __attribute__((address_space(1))) void*)g,
        (__attribute__((address_space(3))) void*)l, 16, 0, 0);
}

__device__ __forceinline__ ushort_t f2bf(float f) {
    __hip_bfloat16 b = __float2bfloat16(f);
    return *(ushort_t*)&b;
}

// x [256][16384] f32 -> xb [16384][256] bf16 (transpose + convert)
__global__ __launch_bounds__(256) void k_transpose(const float* __restrict__ x,
                                                   ushort_t* __restrict__ xb) {
    __shared__ float tile[64][65];
    int t = threadIdx.x;
    int l0 = blockIdx.x * 64;
    int c0 = blockIdx.y * 64;
#pragma unroll
    for (int r = 0; r < 16; ++r) {
        int c = r * 4 + (t >> 6);
        int l = t & 63;
        tile[c][l] = x[(size_t)(c0 + c) * L_LEN + l0 + l];
    }
    __syncthreads();
    int l = t >> 2;
    int cq = (t & 3) * 16;
    ushort_t tmp[16];
#pragma unroll
    for (int i = 0; i < 16; ++i) tmp[i] = f2bf(tile[cq + i][l]);
    ushort_t* dst = xb + (size_t)(l0 + l) * C_CH + c0 + cq;
    *(uint4*)dst = *(uint4*)&tmp[0];
    *(uint4*)(dst + 8) = *(uint4*)&tmp[8];
}

// w_tr [16][256][256] f32 -> Ag [m=256][k=h*256+c] bf16
__global__ __launch_bounds__(256) void k_aconv(const float* __restrict__ wtr,
                                               ushort_t* __restrict__ Ag) {
    int tid = blockIdx.x * 256 + threadIdx.x;
    int base = tid * 8;                 // element index in Ag (1M total)
    int m = base >> 12;
    int k = base & 4095;
    int h = k >> 8, c = k & 255;
    const float* src = wtr + ((size_t)h * C_CH + m) * C_CH + c;
    ushort_t tmp[8];
#pragma unroll
    for (int i = 0; i < 8; ++i) tmp[i] = f2bf(src[i]);
    *(uint4*)(Ag + base) = *(uint4*)tmp;
}

__global__ void k_bias(const float* __restrict__ btr, float* __restrict__ bias) {
    int o = threadIdx.x;
    float s = 0.f;
#pragma unroll
    for (int h = 0; h < H_HEADS; ++h) s += btr[h * C_CH + o];
    bias[o] = s;
}

// conv partials: grid (32 l-tiles of 512, 16 c-chunks of 16), 256 thr.
// thread: hq = t>>6 -> heads hq*4..+3, lg = t&63 -> 8 l's. atomicAdd into scores.
__global__ __launch_bounds__(256) void k_conv(const float* __restrict__ x,
                                              const float* __restrict__ wh,
                                              float* __restrict__ scores) {
    __shared__ float xs[16][528];
    __shared__ float wl[16][16][16];
    int t = threadIdx.x;
    int l0 = blockIdx.x * 512;
    int c0 = blockIdx.y * 16;
#pragma unroll
    for (int r = 0; r < 16; ++r) {      // stage w (pad 15->16): 16h x 16c x 16w
        int idx = r * 256 + t;
        int h = idx >> 8, rem = idx & 255;
        int c = rem >> 4, w = rem & 15;
        float v = 0.f;
        if (w < 15) v = wh[((size_t)h * C_CH + c0 + c) * W_WIN + w];
        wl[h][c][w] = v;
    }
    for (int r = 0; r < 33; ++r) {      // stage x window [l0-8, l0+520): 16c x 528
        int idx = r * 256 + t;
        int c = idx / 528, col = idx % 528;
        int l = l0 - 8 + col;
        float v = 0.f;
        if (l >= 0 && l < L_LEN) v = x[(size_t)(c0 + c) * L_LEN + l];
        xs[c][col] = v;
    }
    __syncthreads();
    int lg = t & 63, hq = t >> 6;
    float sc[4][8];
#pragma unroll
    for (int a = 0; a < 4; ++a)
#pragma unroll
        for (int j = 0; j < 8; ++j) sc[a][j] = 0.f;

    for (int c = 0; c < 16; ++c) {
        float xr[24];
        const float4* xp = (const float4*)&xs[c][lg * 8];
#pragma unroll
        for (int i = 0; i < 6; ++i) {
            float4 v = xp[i];
            xr[i * 4 + 0] = v.x; xr[i * 4 + 1] = v.y;
            xr[i * 4 + 2] = v.z; xr[i * 4 + 3] = v.w;
        }
#pragma unroll
        for (int hh = 0; hh < 4; ++hh) {
            int h = hq * 4 + hh;
            const float4* wp = (const float4*)&wl[h][c][0];
            float4 w0 = wp[0], w1 = wp[1], w2 = wp[2], w3 = wp[3];
            float wv[16] = {w0.x, w0.y, w0.z, w0.w, w1.x, w1.y, w1.z, w1.w,
                            w2.x, w2.y, w2.z, w2.w, w3.x, w3.y, w3.z, w3.w};
#pragma unroll
            for (int w = 0; w < 15; ++w)
#pragma unroll
                for (int j = 0; j < 8; ++j)
                    sc[hh][j] = fmaf(wv[w], xr[j + w + 1], sc[hh][j]);
        }
    }
#pragma unroll
    for (int hh = 0; hh < 4; ++hh) {
        int h = hq * 4 + hh;
        float* dst = scores + (size_t)h * L_LEN + l0 + lg * 8;
#pragma unroll
        for (int j = 0; j < 8; ++j) atomicAdd(&dst[j], sc[hh][j]);
    }
}

// softmax over L per head (in-place scores -> focus), adds b_heads. 16 blocks x 1024.
__global__ __launch_bounds__(1024) void k_softmax(float* __restrict__ scfoc,
                                                  const float* __restrict__ bh) {
    __shared__ float red[17];
    int h = blockIdx.x, t = threadIdx.x;
    int wid = t >> 6, ln = t & 63;
    float b = bh[h];
    float s[16];
#pragma unroll
    for (int r = 0; r < 16; ++r)
        s[r] = b + scfoc[(size_t)h * L_LEN + r * 1024 + t];
    float mx = s[0];
#pragma unroll
    for (int r = 1; r < 16; ++r) mx = fmaxf(mx, s[r]);
    for (int o = 32; o > 0; o >>= 1) mx = fmaxf(mx, __shfl_xor(mx, o));
    if (ln == 0) red[wid] = mx;
    __syncthreads();
    if (t == 0) {
        float m2 = red[0];
        for (int i = 1; i < 16; ++i) m2 = fmaxf(m2, red[i]);
        red[16] = m2;
    }
    __syncthreads();
    float M = red[16];
    float sum = 0.f;
#pragma unroll
    for (int r = 0; r < 16; ++r) {
        float e = __expf(s[r] - M);
        s[r] = e;
        sum += e;
    }
    for (int o = 32; o > 0; o >>= 1) sum += __shfl_xor(sum, o);
    __syncthreads();
    if (ln == 0) red[wid] = sum;
    __syncthreads();
    if (t == 0) {
        float s2 = 0.f;
        for (int i = 0; i < 16; ++i) s2 += red[i];
        red[16] = s2;
    }
    __syncthreads();
    float inv = 1.0f / red[16];
#pragma unroll
    for (int r = 0; r < 16; ++r)
        scfoc[(size_t)h * L_LEN + r * 1024 + t] = s[r] * inv;
}

// GEMM: out[256][16384] = A[256][4096] @ B(=xb^T), per-head focus-scaled accum.
// BM=128 BN=64 BK=64, 256 thr (4 waves, wave tile 64x32), grid (256 n, 2 m)
#define LDSA 16384
#define LDSB 8192
#define LBUF (LDSA + LDSB)

__global__ __launch_bounds__(256, 2) void k_gemm(const ushort_t* __restrict__ Ag,
                                                 const ushort_t* __restrict__ xb,
                                                 const float* __restrict__ foc,
                                                 const float* __restrict__ bias,
                                                 float* __restrict__ out) {
    __shared__ char lds[2 * LBUF];
    int t = threadIdx.x;
    int w = t >> 6, lane = t & 63;
    int m0 = blockIdx.y * 128, n0 = blockIdx.x * 64;
    int wr = w >> 1, wc = w & 1;
    int r = lane & 15, q = lane >> 4;

    const f32x4 vzero = {0.f, 0.f, 0.f, 0.f};
    f32x4 oacc[4][2], hacc[4][2];
#pragma unroll
    for (int i = 0; i < 4; ++i)
#pragma unroll
        for (int j = 0; j < 2; ++j) { oacc[i][j] = vzero; hacc[i][j] = vzero; }

    auto stageA = [&](int buf, int kt) {
        const ushort_t* s = Ag + (size_t)(m0 + (t >> 3)) * 4096 + kt * 64 + (t & 7) * 8;
        char* base = lds + buf * LBUF + (w << 10);
#pragma unroll
        for (int j = 0; j < 4; ++j)
            gll16(s + (size_t)j * 32 * 4096, base + j * 4096);
    };
    auto stageB = [&](int buf, int kt) {
        int kc = (kt & 3) * 64;                       // column within head = c
        const ushort_t* s = xb + (size_t)(n0 + (t >> 3)) * 256 + kc + (t & 7) * 8;
        char* base = lds + buf * LBUF + LDSA + (w << 10);
#pragma unroll
        for (int j = 0; j < 2; ++j)
            gll16(s + (size_t)j * 32 * 256, base + j * 4096);
    };
    auto compute = [&](int buf) {
        char* Ab = lds + buf * LBUF;
        char* Bb = Ab + LDSA;
#pragma unroll
        for (int kk = 0; kk < 2; ++kk) {
            bf16x8 a[4], bfr[2];
#pragma unroll
            for (int i = 0; i < 4; ++i)
                a[i] = *(const bf16x8*)(Ab + (wr * 64 + i * 16 + r) * 128 + kk * 64 + q * 16);
#pragma unroll
            for (int j = 0; j < 2; ++j)
                bfr[j] = *(const bf16x8*)(Bb + (wc * 32 + j * 16 + r) * 128 + kk * 64 + q * 16);
#pragma unroll
            for (int i = 0; i < 4; ++i)
#pragma unroll
                for (int j = 0; j < 2; ++j)
                    hacc[i][j] = __builtin_amdgcn_mfma_f32_16x16x32_bf16(a[i], bfr[j], hacc[i][j], 0, 0, 0);
        }
    };

    stageA(0, 0);
    stageB(0, 0);
    __syncthreads();

    for (int h = 0; h < H_HEADS; ++h) {
        float f0 = foc[(size_t)h * L_LEN + n0 + wc * 32 + r];
        float f1 = foc[(size_t)h * L_LEN + n0 + wc * 32 + 16 + r];
#pragma unroll
        for (int qq = 0; qq < 4; ++qq) {
            int kt = h * 4 + qq;
            int buf = qq & 1;
            if (kt < 63) { stageA(buf ^ 1, kt + 1); stageB(buf ^ 1, kt + 1); }
            compute(buf);
            __syncthreads();
        }
#pragma unroll
        for (int i = 0; i < 4; ++i) {
            oacc[i][0] += hacc[i][0] * f0;
            oacc[i][1] += hacc[i][1] * f1;
            hacc[i][0] = vzero;
            hacc[i][1] = vzero;
        }
    }

#pragma unroll
    for (int i = 0; i < 4; ++i) {
        int mrow = m0 + wr * 64 + i * 16 + q * 4;
        float4 bv = *(const float4*)&bias[mrow];
        float bvr[4] = {bv.x, bv.y, bv.z, bv.w};
#pragma unroll
        for (int j = 0; j < 2; ++j) {
            int n = n0 + wc * 32 + j * 16 + r;
#pragma unroll
            for (int rr = 0; rr < 4; ++rr)
                out[(size_t)(mrow + rr) * L_LEN + n] = oacc[i][j][rr] + bvr[rr];
        }
    }
}

extern "C" void kernel_launch(void* const* d_in, const int* in_sizes, int n_in,
                              void* d_out, int out_size, void* d_ws, size_t ws_size,
                              hipStream_t stream) {
    const float* x   = (const float*)d_in[0];
    const float* wh  = (const float*)d_in[1];
    const float* bh  = (const float*)d_in[2];
    const float* wtr = (const float*)d_in[3];
    const float* btr = (const float*)d_in[4];
    float* out = (float*)d_out;
    char* ws = (char*)d_ws;

    ushort_t* Ag    = (ushort_t*)(ws);
    ushort_t* xb    = (ushort_t*)(ws + ((size_t)2 << 20));
    float*    scfoc = (float*)(ws + ((size_t)10 << 20));
    float*    bias  = (float*)(ws + ((size_t)11 << 20));

    hipMemsetAsync(scfoc, 0, (size_t)H_HEADS * L_LEN * sizeof(float), stream);
    k_transpose<<<dim3(256, 4), 256, 0, stream>>>(x, xb);
    k_aconv<<<dim3(512), 256, 0, stream>>>(wtr, Ag);
    k_bias<<<1, 256, 0, stream>>>(btr, bias);
    k_conv<<<dim3(32, 16), 256, 0, stream>>>(x, wh, scfoc);
    k_softmax<<<16, 1024, 0, stream>>>(scfoc, bh);
    k_gemm<<<dim3(256, 2), 256, 0, stream>>>(Ag, xb, scfoc, bias, out);
}

// Round 3
// 149.111 us; speedup vs baseline: 1.8506x; 1.8506x over previous
//
#include <hip/hip_runtime.h>
#include <hip/hip_bf16.h>

#define L_LEN 16384
#define C_CH  256
#define H_HEADS 16
#define W_WIN 15

typedef __attribute__((ext_vector_type(8))) short bf16x8;
typedef __attribute__((ext_vector_type(4))) float f32x4;
typedef unsigned short ushort_t;

// ---------------- ws layout (bytes) ----------------
// Ag    : [256][4096] bf16  @ 0        (2 MB)
// xb    : [16384][256] bf16 @ 2 MB     (8 MB)
// scfoc : [16][16384] f32   @ 10 MB    (1 MB)  scores -> focus (in-place)
// bias  : [256] f32         @ 11 MB    (1 KB)
// awf   : [15][8][64][8] bf16 @ 11M+4K (120 KB)  A-fragment layout of w_heads
// total ~11.13 MB

__device__ __forceinline__ void gll16(const void* g, void* l) {
    __builtin_amdgcn_global_load_lds(
        (const __attribute__((address_space(1))) void*)g,
        (__attribute__((address_space(3))) void*)l, 16, 0, 0);
}

__device__ __forceinline__ ushort_t f2bf(float f) {
    __hip_bfloat16 b = __float2bfloat16(f);
    return *(ushort_t*)&b;
}

// x [256][16384] f32 -> xb [16384][256] bf16 (transpose + convert)
__global__ __launch_bounds__(256) void k_transpose(const float* __restrict__ x,
                                                   ushort_t* __restrict__ xb) {
    __shared__ float tile[64][65];
    int t = threadIdx.x;
    int l0 = blockIdx.x * 64;
    int c0 = blockIdx.y * 64;
#pragma unroll
    for (int r = 0; r < 16; ++r) {
        int c = r * 4 + (t >> 6);
        int l = t & 63;
        tile[c][l] = x[(size_t)(c0 + c) * L_LEN + l0 + l];
    }
    __syncthreads();
    int l = t >> 2;
    int cq = (t & 3) * 16;
    ushort_t tmp[16];
#pragma unroll
    for (int i = 0; i < 16; ++i) tmp[i] = f2bf(tile[cq + i][l]);
    ushort_t* dst = xb + (size_t)(l0 + l) * C_CH + c0 + cq;
    *(uint4*)dst = *(uint4*)&tmp[0];
    *(uint4*)(dst + 8) = *(uint4*)&tmp[8];
}

// w_tr [16][256][256] f32 -> Ag [m=256][k=h*256+c] bf16
__global__ __launch_bounds__(256) void k_aconv(const float* __restrict__ wtr,
                                               ushort_t* __restrict__ Ag) {
    int tid = blockIdx.x * 256 + threadIdx.x;
    int base = tid * 8;
    int m = base >> 12;
    int k = base & 4095;
    int h = k >> 8, c = k & 255;
    const float* src = wtr + ((size_t)h * C_CH + m) * C_CH + c;
    ushort_t tmp[8];
#pragma unroll
    for (int i = 0; i < 8; ++i) tmp[i] = f2bf(src[i]);
    *(uint4*)(Ag + base) = *(uint4*)tmp;
}

__global__ void k_bias(const float* __restrict__ btr, float* __restrict__ bias) {
    int o = threadIdx.x;
    float s = 0.f;
#pragma unroll
    for (int h = 0; h < H_HEADS; ++h) s += btr[h * C_CH + o];
    bias[o] = s;
}

// w_heads [16][256][15] f32 -> awf: MFMA A-fragment order.
// awf[((w*8+kt)*64+lane)*8 + e] = bf16(wh[h=lane&15][c=kt*32+(lane>>4)*8+e][w])
__global__ __launch_bounds__(256) void k_wprep(const float* __restrict__ wh,
                                               ushort_t* __restrict__ awf) {
    int tid = blockIdx.x * 256 + threadIdx.x;   // 61440 total
    int e = tid & 7;
    int lane = (tid >> 3) & 63;
    int ktw = tid >> 9;                          // w*8+kt, 0..119
    int w = ktw >> 3, kt = ktw & 7;
    int h = lane & 15;
    int c = kt * 32 + (lane >> 4) * 8 + e;
    awf[tid] = f2bf(wh[((size_t)h * C_CH + c) * W_WIN + w]);
}

// conv via MFMA: scores[16][L]. grid 512 blocks (l-tile 32), 128 thr (2 waves).
// LDS: xb halo rows [n0-8, n0+40) = 48 rows x 256c bf16, XOR-swizzled.
// Per wave (16 l's): for w in 0..14, kt in 0..7: mfma(awf-frag, shifted-row B-frag).
__global__ __launch_bounds__(128) void k_convm(const ushort_t* __restrict__ xb,
                                               const ushort_t* __restrict__ awf,
                                               float* __restrict__ scores) {
    __shared__ char xs[48 * 512];
    int t = threadIdx.x;
    int n0 = blockIdx.x * 32;
#pragma unroll
    for (int i = 0; i < 12; ++i) {               // 1536 16B-chunks / 128 thr
        int chunk = t + i * 128;
        int rr = chunk >> 5;
        int cb = (chunk & 31) * 16;              // byte offset in row
        int l = n0 - 8 + rr;
        uint4 v = {0u, 0u, 0u, 0u};
        if (l >= 0 && l < L_LEN) v = *(const uint4*)(xb + (size_t)l * C_CH + (cb >> 1));
        *(uint4*)(&xs[rr * 512 + (cb ^ ((rr & 7) << 4))]) = v;
    }
    __syncthreads();
    int wv = t >> 6, lane = t & 63;
    int r = lane & 15, q = lane >> 4;
    const f32x4 vzero = {0.f, 0.f, 0.f, 0.f};
    f32x4 acc[4] = {vzero, vzero, vzero, vzero};
    for (int w = 0; w < 15; ++w) {
        int rr = wv * 16 + r + w + 1;            // shifted B row (halo handles w-7)
        const char* rowp = &xs[rr * 512];
        int sw = (rr & 7) << 4;
#pragma unroll
        for (int kt = 0; kt < 8; ++kt) {
            bf16x8 a = *(const bf16x8*)(awf + (size_t)(((w * 8 + kt) * 64 + lane) * 8));
            bf16x8 b = *(const bf16x8*)(rowp + ((kt * 64 + q * 16) ^ sw));
            acc[kt & 3] = __builtin_amdgcn_mfma_f32_16x16x32_bf16(a, b, acc[kt & 3], 0, 0, 0);
        }
    }
    f32x4 s = acc[0] + acc[1] + acc[2] + acc[3];
    int nb = n0 + wv * 16;
#pragma unroll
    for (int e = 0; e < 4; ++e)
        scores[(size_t)(q * 4 + e) * L_LEN + nb + r] = s[e];
}

// softmax over L per head (in-place scores -> focus), adds b_heads. 16 blocks x 1024.
__global__ __launch_bounds__(1024) void k_softmax(float* __restrict__ scfoc,
                                                  const float* __restrict__ bh) {
    __shared__ float red[17];
    int h = blockIdx.x, t = threadIdx.x;
    int wid = t >> 6, ln = t & 63;
    float b = bh[h];
    float s[16];
#pragma unroll
    for (int r = 0; r < 16; ++r)
        s[r] = b + scfoc[(size_t)h * L_LEN + r * 1024 + t];
    float mx = s[0];
#pragma unroll
    for (int r = 1; r < 16; ++r) mx = fmaxf(mx, s[r]);
    for (int o = 32; o > 0; o >>= 1) mx = fmaxf(mx, __shfl_xor(mx, o));
    if (ln == 0) red[wid] = mx;
    __syncthreads();
    if (t == 0) {
        float m2 = red[0];
        for (int i = 1; i < 16; ++i) m2 = fmaxf(m2, red[i]);
        red[16] = m2;
    }
    __syncthreads();
    float M = red[16];
    float sum = 0.f;
#pragma unroll
    for (int r = 0; r < 16; ++r) {
        float e = __expf(s[r] - M);
        s[r] = e;
        sum += e;
    }
    for (int o = 32; o > 0; o >>= 1) sum += __shfl_xor(sum, o);
    __syncthreads();
    if (ln == 0) red[wid] = sum;
    __syncthreads();
    if (t == 0) {
        float s2 = 0.f;
        for (int i = 0; i < 16; ++i) s2 += red[i];
        red[16] = s2;
    }
    __syncthreads();
    float inv = 1.0f / red[16];
#pragma unroll
    for (int r = 0; r < 16; ++r)
        scfoc[(size_t)h * L_LEN + r * 1024 + t] = s[r] * inv;
}

// GEMM: out[256][16384] = A[256][4096] @ B(=xb^T), per-head focus-scaled accum.
// m97 structure: BM=128 BN=128 BK=64, 256 thr (4 waves 2x2, wave tile 64x64).
// grid (128 n, 2 m) = 256 blocks.
#define GLDSA 16384
#define GBUF  32768

__global__ __launch_bounds__(256, 2) void k_gemm(const ushort_t* __restrict__ Ag,
                                                 const ushort_t* __restrict__ xb,
                                                 const float* __restrict__ foc,
                                                 const float* __restrict__ bias,
                                                 float* __restrict__ out) {
    __shared__ char lds[2 * GBUF];
    int t = threadIdx.x;
    int w = t >> 6, lane = t & 63;
    int m0 = blockIdx.y * 128, n0 = blockIdx.x * 128;
    int wr = w >> 1, wc = w & 1;
    int r = lane & 15, q = lane >> 4;

    const f32x4 vzero = {0.f, 0.f, 0.f, 0.f};
    f32x4 oacc[4][4], hacc[4][4];
#pragma unroll
    for (int i = 0; i < 4; ++i)
#pragma unroll
        for (int j = 0; j < 4; ++j) { oacc[i][j] = vzero; hacc[i][j] = vzero; }

    auto stageA = [&](int buf, int kt) {
        const ushort_t* s = Ag + (size_t)(m0 + (t >> 3)) * 4096 + kt * 64 + (t & 7) * 8;
        char* base = lds + buf * GBUF + (w << 10);
#pragma unroll
        for (int j = 0; j < 4; ++j)
            gll16(s + (size_t)j * 32 * 4096, base + j * 4096);
    };
    auto stageB = [&](int buf, int kt) {
        int kc = (kt & 3) * 64;                   // column within head = c
        const ushort_t* s = xb + (size_t)(n0 + (t >> 3)) * 256 + kc + (t & 7) * 8;
        char* base = lds + buf * GBUF + GLDSA + (w << 10);
#pragma unroll
        for (int j = 0; j < 4; ++j)
            gll16(s + (size_t)j * 32 * 256, base + j * 4096);
    };
    auto compute = [&](int buf) {
        char* Ab = lds + buf * GBUF;
        char* Bb = Ab + GLDSA;
#pragma unroll
        for (int kk = 0; kk < 2; ++kk) {
            bf16x8 a[4], bfr[4];
#pragma unroll
            for (int i = 0; i < 4; ++i)
                a[i] = *(const bf16x8*)(Ab + (wr * 64 + i * 16 + r) * 128 + kk * 64 + q * 16);
#pragma unroll
            for (int j = 0; j < 4; ++j)
                bfr[j] = *(const bf16x8*)(Bb + (wc * 64 + j * 16 + r) * 128 + kk * 64 + q * 16);
#pragma unroll
            for (int i = 0; i < 4; ++i)
#pragma unroll
                for (int j = 0; j < 4; ++j)
                    hacc[i][j] = __builtin_amdgcn_mfma_f32_16x16x32_bf16(a[i], bfr[j], hacc[i][j], 0, 0, 0);
        }
    };

    stageA(0, 0);
    stageB(0, 0);
    __syncthreads();

    for (int h = 0; h < H_HEADS; ++h) {
        float f[4];
#pragma unroll
        for (int j = 0; j < 4; ++j)
            f[j] = foc[(size_t)h * L_LEN + n0 + wc * 64 + j * 16 + r];
#pragma unroll
        for (int qq = 0; qq < 4; ++qq) {
            int kt = h * 4 + qq;
            int buf = qq & 1;
            if (kt < 63) { stageA(buf ^ 1, kt + 1); stageB(buf ^ 1, kt + 1); }
            compute(buf);
            __syncthreads();
        }
#pragma unroll
        for (int i = 0; i < 4; ++i)
#pragma unroll
            for (int j = 0; j < 4; ++j) {
                oacc[i][j] += hacc[i][j] * f[j];
                hacc[i][j] = vzero;
            }
    }

#pragma unroll
    for (int i = 0; i < 4; ++i) {
        int mrow = m0 + wr * 64 + i * 16 + q * 4;
        float4 bv = *(const float4*)&bias[mrow];
        float bvr[4] = {bv.x, bv.y, bv.z, bv.w};
#pragma unroll
        for (int j = 0; j < 4; ++j) {
            int n = n0 + wc * 64 + j * 16 + r;
#pragma unroll
            for (int rr = 0; rr < 4; ++rr)
                out[(size_t)(mrow + rr) * L_LEN + n] = oacc[i][j][rr] + bvr[rr];
        }
    }
}

extern "C" void kernel_launch(void* const* d_in, const int* in_sizes, int n_in,
                              void* d_out, int out_size, void* d_ws, size_t ws_size,
                              hipStream_t stream) {
    const float* x   = (const float*)d_in[0];
    const float* wh  = (const float*)d_in[1];
    const float* bh  = (const float*)d_in[2];
    const float* wtr = (const float*)d_in[3];
    const float* btr = (const float*)d_in[4];
    float* out = (float*)d_out;
    char* ws = (char*)d_ws;

    ushort_t* Ag    = (ushort_t*)(ws);
    ushort_t* xb    = (ushort_t*)(ws + ((size_t)2 << 20));
    float*    scfoc = (float*)(ws + ((size_t)10 << 20));
    float*    bias  = (float*)(ws + ((size_t)11 << 20));
    ushort_t* awf   = (ushort_t*)(ws + ((size_t)11 << 20) + 4096);

    k_transpose<<<dim3(256, 4), 256, 0, stream>>>(x, xb);
    k_aconv<<<dim3(512), 256, 0, stream>>>(wtr, Ag);
    k_bias<<<1, 256, 0, stream>>>(btr, bias);
    k_wprep<<<dim3(240), 256, 0, stream>>>(wh, awf);
    k_convm<<<dim3(512), 128, 0, stream>>>(xb, awf, scfoc);
    k_softmax<<<16, 1024, 0, stream>>>(scfoc, bh);
    k_gemm<<<dim3(128, 2), 256, 0, stream>>>(Ag, xb, scfoc, bias, out);
}

// Round 4
// 138.625 us; speedup vs baseline: 1.9906x; 1.0756x over previous
//
#include <hip/hip_runtime.h>
#include <hip/hip_bf16.h>

#define L_LEN 16384
#define C_CH  256
#define H_HEADS 16
#define W_WIN 15

typedef __attribute__((ext_vector_type(8))) short bf16x8;
typedef __attribute__((ext_vector_type(4))) float f32x4;
typedef unsigned short ushort_t;

// ---------------- ws layout (bytes) ----------------
// Ag     : [256][4096] bf16, per-128B-window XOR-swizzled  @ 0      (2 MB)
// xb     : [16384][256] bf16, per-row XOR-swizzled         @ 2 MB   (8 MB)
// scores : [16][16384] f32 (raw conv out, no b_heads)      @ 10 MB  (1 MB)
// awf    : [15][8][64][8] bf16 A-fragments of w_heads      @ 11 MB  (120 KB)
// mpart  : [16][8] f32   @ 11M+128K
// zpart  : [16][8] f32   @ +512
// MZ     : [16] float2   @ +1024
// bias   : [256] f32     @ +2048
// Swizzle convention: xb row byte b holds orig byte (b ^ ((l&7)<<4));
// Ag: within each 128-B k-window. Readers XOR on ds_read; gll16 stays linear.

__device__ __forceinline__ void gll16(const void* g, void* l) {
    __builtin_amdgcn_global_load_lds(
        (const __attribute__((address_space(1))) void*)g,
        (__attribute__((address_space(3))) void*)l, 16, 0, 0);
}

__device__ __forceinline__ ushort_t f2bf(float f) {
    __hip_bfloat16 b = __float2bfloat16(f);
    return *(ushort_t*)&b;
}

// x [256][16384] f32 -> xb_swz [16384][256] bf16 (transpose + convert + swizzle)
__global__ __launch_bounds__(256) void k_transpose(const float* __restrict__ x,
                                                   ushort_t* __restrict__ xb) {
    __shared__ float tile[64][65];
    int t = threadIdx.x;
    int l0 = blockIdx.x * 64;
    int c0 = blockIdx.y * 64;
#pragma unroll
    for (int r = 0; r < 16; ++r) {
        int c = r * 4 + (t >> 6);
        int l = t & 63;
        tile[c][l] = x[(size_t)(c0 + c) * L_LEN + l0 + l];
    }
    __syncthreads();
    int l = t >> 2;
    int cq = (t & 3) * 16;
    ushort_t tmp[16];
#pragma unroll
    for (int i = 0; i < 16; ++i) tmp[i] = f2bf(tile[cq + i][l]);
    char* rowp = (char*)(xb + (size_t)(l0 + l) * C_CH);
    int swz = (l & 7) << 4;
    int b0 = (c0 + cq) * 2;
    *(uint4*)(rowp + (b0 ^ swz)) = *(uint4*)&tmp[0];
    *(uint4*)(rowp + ((b0 + 16) ^ swz)) = *(uint4*)&tmp[8];
}

// w_tr [16][256][256] f32 -> Ag_swz [m][k-windows of 64, 128B XOR-swizzled] bf16
__global__ __launch_bounds__(256) void k_aconv(const float* __restrict__ wtr,
                                               ushort_t* __restrict__ Ag) {
    int tid = blockIdx.x * 256 + threadIdx.x;   // 131072 chunks of 16 B
    size_t D = (size_t)tid * 16;
    int m = (int)(D >> 13);
    int inner = (int)(D & 8191);
    int kt = inner >> 7, wb = inner & 127;
    int ob = kt * 128 + (wb ^ ((m & 7) << 4));  // orig byte within row
    int k0 = ob >> 1;
    int h = k0 >> 8, c = k0 & 255;
    const float* src = wtr + ((size_t)h * C_CH + m) * C_CH + c;
    ushort_t tmp[8];
#pragma unroll
    for (int i = 0; i < 8; ++i) tmp[i] = f2bf(src[i]);
    *(uint4*)((char*)Ag + D) = *(uint4*)tmp;
}

// w_heads [16][256][15] f32 -> awf MFMA A-fragment order
__global__ __launch_bounds__(256) void k_wprep(const float* __restrict__ wh,
                                               ushort_t* __restrict__ awf) {
    int tid = blockIdx.x * 256 + threadIdx.x;   // 61440
    int e = tid & 7;
    int lane = (tid >> 3) & 63;
    int ktw = tid >> 9;                          // w*8+kt
    int w = ktw >> 3, kt = ktw & 7;
    int h = lane & 15;
    int c = kt * 32 + (lane >> 4) * 8 + e;
    awf[tid] = f2bf(wh[((size_t)h * C_CH + c) * W_WIN + w]);
}

// conv via MFMA -> scores[16][L]. grid 512 (l-tile 32), 128 thr (2 waves).
__global__ __launch_bounds__(128) void k_convm(const ushort_t* __restrict__ xb,
                                               const ushort_t* __restrict__ awf,
                                               float* __restrict__ scores) {
    __shared__ char xs[48 * 512];
    int t = threadIdx.x;
    int n0 = blockIdx.x * 32;
#pragma unroll
    for (int i = 0; i < 12; ++i) {               // 1536 chunks, linear gll16
        int chunk = t + i * 128;
        int rr = chunk >> 5;
        int cb = (chunk & 31) * 16;
        int l = n0 - 8 + rr;
        int lc = l < 0 ? 0 : (l >= L_LEN ? L_LEN - 1 : l);
        gll16((const char*)xb + (size_t)lc * 512 + cb, xs + chunk * 16);
    }
    __syncthreads();
    if (n0 == 0 || n0 == L_LEN - 32) {           // zero OOB halo rows
        int rbase = (n0 == 0) ? 0 : 40;
        uint4 z = {0u, 0u, 0u, 0u};
#pragma unroll
        for (int i = 0; i < 2; ++i) {
            int ch = t + i * 128;
            *(uint4*)(xs + rbase * 512 + ch * 16) = z;
        }
        __syncthreads();
    }
    int wv = t >> 6, lane = t & 63;
    int r = lane & 15, q = lane >> 4;
    const f32x4 vzero = {0.f, 0.f, 0.f, 0.f};
    f32x4 acc[4] = {vzero, vzero, vzero, vzero};
    for (int w = 0; w < 15; ++w) {
        int rr = wv * 16 + r + w + 1;
        const char* rowp = &xs[rr * 512];
        int sw = (rr & 7) << 4;
#pragma unroll
        for (int kt = 0; kt < 8; ++kt) {
            bf16x8 a = *(const bf16x8*)(awf + (size_t)(((w * 8 + kt) * 64 + lane) * 8));
            bf16x8 b = *(const bf16x8*)(rowp + ((kt * 64 + q * 16) ^ sw));
            acc[kt & 3] = __builtin_amdgcn_mfma_f32_16x16x32_bf16(a, b, acc[kt & 3], 0, 0, 0);
        }
    }
    f32x4 s = acc[0] + acc[1] + acc[2] + acc[3];
    int nb = n0 + wv * 16;
#pragma unroll
    for (int e = 0; e < 4; ++e)
        scores[(size_t)(q * 4 + e) * L_LEN + nb + r] = s[e];
}

// partial softmax stats: 128 blocks (h = b>>3, seg = b&7) x 256 thr, 2048 elems each
__global__ __launch_bounds__(256) void k_smred(const float* __restrict__ scores,
                                               float* __restrict__ mpart,
                                               float* __restrict__ zpart) {
    __shared__ float red[8];
    int b = blockIdx.x;
    int h = b >> 3, seg = b & 7;
    int t = threadIdx.x, wid = t >> 6, ln = t & 63;
    const float* sp = scores + (size_t)h * L_LEN + seg * 2048;
    float v[8];
    float mx = -1e30f;
#pragma unroll
    for (int i = 0; i < 8; ++i) {
        v[i] = sp[i * 256 + t];
        mx = fmaxf(mx, v[i]);
    }
    for (int o = 32; o > 0; o >>= 1) mx = fmaxf(mx, __shfl_xor(mx, o));
    if (ln == 0) red[wid] = mx;
    __syncthreads();
    if (t == 0) {
        float m2 = fmaxf(fmaxf(red[0], red[1]), fmaxf(red[2], red[3]));
        red[4] = m2;
    }
    __syncthreads();
    float M = red[4];
    float s = 0.f;
#pragma unroll
    for (int i = 0; i < 8; ++i) s += __expf(v[i] - M);
    for (int o = 32; o > 0; o >>= 1) s += __shfl_xor(s, o);
    if (ln == 0) red[wid] = s;
    __syncthreads();
    if (t == 0) {
        mpart[b] = M;
        zpart[b] = red[0] + red[1] + red[2] + red[3];
    }
}

// combine partials -> MZ[h] = {M_h, 1/Z_h}; also head-summed bias
__global__ void k_scalars(const float* __restrict__ btr,
                          const float* __restrict__ mpart,
                          const float* __restrict__ zpart,
                          float* __restrict__ bias,
                          float2* __restrict__ MZ) {
    int t = threadIdx.x;
    float s = 0.f;
#pragma unroll
    for (int h = 0; h < H_HEADS; ++h) s += btr[h * C_CH + t];
    bias[t] = s;
    if (t < H_HEADS) {
        float M = -1e30f;
#pragma unroll
        for (int g = 0; g < 8; ++g) M = fmaxf(M, mpart[t * 8 + g]);
        float Z = 0.f;
#pragma unroll
        for (int g = 0; g < 8; ++g) Z += zpart[t * 8 + g] * __expf(mpart[t * 8 + g] - M);
        float2 r; r.x = M; r.y = 1.0f / Z;
        MZ[t] = r;
    }
}

// GEMM: out[256][16384], B panel (64 KB) LDS-resident, A streamed 16 KB/K-step.
// BM=128 BN=128 BK=64, 256 thr (4 waves 2x2), grid (128 n, 2 m) = 256 blocks.
#define BRES 65536
#define ATS  16384

__global__ __launch_bounds__(256, 1) void k_gemm(const ushort_t* __restrict__ Ag,
                                                 const ushort_t* __restrict__ xb,
                                                 const float* __restrict__ scores,
                                                 const float2* __restrict__ MZ,
                                                 const float* __restrict__ bias,
                                                 float* __restrict__ out) {
    __shared__ char lds[BRES + 2 * ATS];   // 96 KB
    int t = threadIdx.x;
    int w = t >> 6, lane = t & 63;
    int m0 = blockIdx.y * 128, n0 = blockIdx.x * 128;
    int wr = w >> 1, wc = w & 1;
    int r = lane & 15, q = lane >> 4;

    // stage B panel: rows n0..n0+128, full 256 c (swizzled content, linear copy)
#pragma unroll
    for (int i = 0; i < 16; ++i) {
        int chunk = t + i * 256;
        int row = chunk >> 5, cb = (chunk & 31) * 16;
        gll16((const char*)xb + (size_t)(n0 + row) * 512 + cb, lds + chunk * 16);
    }
    auto stageA = [&](int buf, int kt) {
        const char* src = (const char*)Ag + (size_t)(m0 + (t >> 3)) * 8192 + kt * 128 + (t & 7) * 16;
        char* dst = lds + BRES + buf * ATS + t * 16;
#pragma unroll
        for (int j = 0; j < 4; ++j)
            gll16(src + (size_t)j * 32 * 8192, dst + j * 4096);
    };
    stageA(0, 0);

    const f32x4 vzero = {0.f, 0.f, 0.f, 0.f};
    f32x4 oacc[4][4], hacc[4][4];
#pragma unroll
    for (int i = 0; i < 4; ++i)
#pragma unroll
        for (int j = 0; j < 4; ++j) { oacc[i][j] = vzero; hacc[i][j] = vzero; }

    __syncthreads();

    for (int h = 0; h < H_HEADS; ++h) {
        float2 mz = MZ[h];
        float f[4];
#pragma unroll
        for (int j = 0; j < 4; ++j) {
            float s = scores[(size_t)h * L_LEN + n0 + wc * 64 + j * 16 + r];
            f[j] = __expf(s - mz.x) * mz.y;
        }
#pragma unroll
        for (int qq = 0; qq < 4; ++qq) {
            int kt = h * 4 + qq;
            int buf = kt & 1;
            if (kt < 63) stageA(buf ^ 1, kt + 1);
            char* Ab = lds + BRES + buf * ATS;
#pragma unroll
            for (int kk = 0; kk < 2; ++kk) {
                bf16x8 a[4], bb[4];
#pragma unroll
                for (int i = 0; i < 4; ++i) {
                    int ar = wr * 64 + i * 16 + r;
                    a[i] = *(const bf16x8*)(Ab + ar * 128 + ((kk * 64 + q * 16) ^ ((ar & 7) << 4)));
                }
#pragma unroll
                for (int j = 0; j < 4; ++j) {
                    int br = wc * 64 + j * 16 + r;
                    bb[j] = *(const bf16x8*)(lds + br * 512 +
                              ((qq * 128 + kk * 64 + q * 16) ^ ((br & 7) << 4)));
                }
#pragma unroll
                for (int i = 0; i < 4; ++i)
#pragma unroll
                    for (int j = 0; j < 4; ++j)
                        hacc[i][j] = __builtin_amdgcn_mfma_f32_16x16x32_bf16(a[i], bb[j], hacc[i][j], 0, 0, 0);
            }
            __syncthreads();
        }
#pragma unroll
        for (int i = 0; i < 4; ++i)
#pragma unroll
            for (int j = 0; j < 4; ++j) {
                oacc[i][j] += hacc[i][j] * f[j];
                hacc[i][j] = vzero;
            }
    }

#pragma unroll
    for (int i = 0; i < 4; ++i) {
        int mrow = m0 + wr * 64 + i * 16 + q * 4;
        float4 bv = *(const float4*)&bias[mrow];
        float bvr[4] = {bv.x, bv.y, bv.z, bv.w};
#pragma unroll
        for (int j = 0; j < 4; ++j) {
            int n = n0 + wc * 64 + j * 16 + r;
#pragma unroll
            for (int rr = 0; rr < 4; ++rr)
                out[(size_t)(mrow + rr) * L_LEN + n] = oacc[i][j][rr] + bvr[rr];
        }
    }
}

extern "C" void kernel_launch(void* const* d_in, const int* in_sizes, int n_in,
                              void* d_out, int out_size, void* d_ws, size_t ws_size,
                              hipStream_t stream) {
    const float* x   = (const float*)d_in[0];
    const float* wh  = (const float*)d_in[1];
    const float* btr = (const float*)d_in[4];
    const float* wtr = (const float*)d_in[3];
    float* out = (float*)d_out;
    char* ws = (char*)d_ws;

    ushort_t* Ag     = (ushort_t*)(ws);
    ushort_t* xb     = (ushort_t*)(ws + ((size_t)2 << 20));
    float*    scores = (float*)(ws + ((size_t)10 << 20));
    ushort_t* awf    = (ushort_t*)(ws + ((size_t)11 << 20));
    char*     sc     = ws + ((size_t)11 << 20) + (128 << 10);
    float*    mpart  = (float*)(sc);
    float*    zpart  = (float*)(sc + 512);
    float2*   MZ     = (float2*)(sc + 1024);
    float*    bias   = (float*)(sc + 2048);

    k_transpose<<<dim3(256, 4), 256, 0, stream>>>(x, xb);
    k_aconv<<<dim3(512), 256, 0, stream>>>(wtr, Ag);
    k_wprep<<<dim3(240), 256, 0, stream>>>(wh, awf);
    k_convm<<<dim3(512), 128, 0, stream>>>(xb, awf, scores);
    k_smred<<<dim3(128), 256, 0, stream>>>(scores, mpart, zpart);
    k_scalars<<<1, 256, 0, stream>>>(btr, mpart, zpart, bias, MZ);
    k_gemm<<<dim3(128, 2), 256, 0, stream>>>(Ag, xb, scores, MZ, bias, out);
}

// Round 5
// 130.694 us; speedup vs baseline: 2.1114x; 1.0607x over previous
//
#include <hip/hip_runtime.h>
#include <hip/hip_bf16.h>

#define L_LEN 16384
#define C_CH  256
#define H_HEADS 16
#define W_WIN 15

typedef __attribute__((ext_vector_type(8))) short bf16x8;
typedef __attribute__((ext_vector_type(4))) float f32x4;
typedef unsigned short ushort_t;

// ---------------- ws layout (bytes) ----------------
// Ag     : [256][4096] bf16, per-128B-window XOR-swizzled  @ 0      (2 MB)
// xb     : [16384][256] bf16, per-row XOR-swizzled         @ 2 MB   (8 MB)
// scores : [16][16384] f32 (raw conv out, no b_heads)      @ 10 MB  (1 MB)
// awf    : [15][8][64][8] bf16 A-fragments of w_heads      @ 11 MB  (120 KB)
// MZ     : [16] float2   @ 11M+128K
// bias   : [256] f32     @ +1024

__device__ __forceinline__ void gll16(const void* g, void* l) {
    __builtin_amdgcn_global_load_lds(
        (const __attribute__((address_space(1))) void*)g,
        (__attribute__((address_space(3))) void*)l, 16, 0, 0);
}

__device__ __forceinline__ ushort_t f2bf(float f) {
    __hip_bfloat16 b = __float2bfloat16(f);
    return *(ushort_t*)&b;
}

// x [256][16384] f32 -> xb_swz [16384][256] bf16 (transpose + convert + swizzle)
__global__ __launch_bounds__(256) void k_transpose(const float* __restrict__ x,
                                                   ushort_t* __restrict__ xb) {
    __shared__ float tile[64][65];
    int t = threadIdx.x;
    int l0 = blockIdx.x * 64;
    int c0 = blockIdx.y * 64;
#pragma unroll
    for (int r = 0; r < 16; ++r) {
        int c = r * 4 + (t >> 6);
        int l = t & 63;
        tile[c][l] = x[(size_t)(c0 + c) * L_LEN + l0 + l];
    }
    __syncthreads();
    int l = t >> 2;
    int cq = (t & 3) * 16;
    ushort_t tmp[16];
#pragma unroll
    for (int i = 0; i < 16; ++i) tmp[i] = f2bf(tile[cq + i][l]);
    char* rowp = (char*)(xb + (size_t)(l0 + l) * C_CH);
    int swz = (l & 7) << 4;
    int b0 = (c0 + cq) * 2;
    *(uint4*)(rowp + (b0 ^ swz)) = *(uint4*)&tmp[0];
    *(uint4*)(rowp + ((b0 + 16) ^ swz)) = *(uint4*)&tmp[8];
}

// w_tr [16][256][256] f32 -> Ag_swz [m][k-windows of 64, 128B XOR-swizzled] bf16
__global__ __launch_bounds__(256) void k_aconv(const float* __restrict__ wtr,
                                               ushort_t* __restrict__ Ag) {
    int tid = blockIdx.x * 256 + threadIdx.x;   // 131072 chunks of 16 B
    size_t D = (size_t)tid * 16;
    int m = (int)(D >> 13);
    int inner = (int)(D & 8191);
    int kt = inner >> 7, wb = inner & 127;
    int ob = kt * 128 + (wb ^ ((m & 7) << 4));  // orig byte within row
    int k0 = ob >> 1;
    int h = k0 >> 8, c = k0 & 255;
    const float* src = wtr + ((size_t)h * C_CH + m) * C_CH + c;
    ushort_t tmp[8];
#pragma unroll
    for (int i = 0; i < 8; ++i) tmp[i] = f2bf(src[i]);
    *(uint4*)((char*)Ag + D) = *(uint4*)tmp;
}

// w_heads [16][256][15] f32 -> awf MFMA A-fragment order
__global__ __launch_bounds__(256) void k_wprep(const float* __restrict__ wh,
                                               ushort_t* __restrict__ awf) {
    int tid = blockIdx.x * 256 + threadIdx.x;   // 61440
    int e = tid & 7;
    int lane = (tid >> 3) & 63;
    int ktw = tid >> 9;                          // w*8+kt
    int w = ktw >> 3, kt = ktw & 7;
    int h = lane & 15;
    int c = kt * 32 + (lane >> 4) * 8 + e;
    awf[tid] = f2bf(wh[((size_t)h * C_CH + c) * W_WIN + w]);
}

// conv via MFMA -> scores[16][L]. grid 512 (l-tile 32), 128 thr (2 waves).
__global__ __launch_bounds__(128) void k_convm(const ushort_t* __restrict__ xb,
                                               const ushort_t* __restrict__ awf,
                                               float* __restrict__ scores) {
    __shared__ char xs[48 * 512];
    int t = threadIdx.x;
    int n0 = blockIdx.x * 32;
#pragma unroll
    for (int i = 0; i < 12; ++i) {               // 1536 chunks, linear gll16
        int chunk = t + i * 128;
        int rr = chunk >> 5;
        int cb = (chunk & 31) * 16;
        int l = n0 - 8 + rr;
        int lc = l < 0 ? 0 : (l >= L_LEN ? L_LEN - 1 : l);
        gll16((const char*)xb + (size_t)lc * 512 + cb, xs + chunk * 16);
    }
    __syncthreads();
    if (n0 == 0 || n0 == L_LEN - 32) {           // zero OOB halo rows
        int rbase = (n0 == 0) ? 0 : 40;
        uint4 z = {0u, 0u, 0u, 0u};
#pragma unroll
        for (int i = 0; i < 2; ++i) {
            int ch = t + i * 128;
            *(uint4*)(xs + rbase * 512 + ch * 16) = z;
        }
        __syncthreads();
    }
    int wv = t >> 6, lane = t & 63;
    int r = lane & 15, q = lane >> 4;
    const f32x4 vzero = {0.f, 0.f, 0.f, 0.f};
    f32x4 acc[4] = {vzero, vzero, vzero, vzero};
    for (int w = 0; w < 15; ++w) {
        int rr = wv * 16 + r + w + 1;
        const char* rowp = &xs[rr * 512];
        int sw = (rr & 7) << 4;
#pragma unroll
        for (int kt = 0; kt < 8; ++kt) {
            bf16x8 a = *(const bf16x8*)(awf + (size_t)(((w * 8 + kt) * 64 + lane) * 8));
            bf16x8 b = *(const bf16x8*)(rowp + ((kt * 64 + q * 16) ^ sw));
            acc[kt & 3] = __builtin_amdgcn_mfma_f32_16x16x32_bf16(a, b, acc[kt & 3], 0, 0, 0);
        }
    }
    f32x4 s = acc[0] + acc[1] + acc[2] + acc[3];
    int nb = n0 + wv * 16;
#pragma unroll
    for (int e = 0; e < 4; ++e)
        scores[(size_t)(q * 4 + e) * L_LEN + nb + r] = s[e];
}

// softmax stats (M,1/Z) per head + head-summed bias. grid 17 x 1024.
__global__ __launch_bounds__(1024) void k_stats(const float* __restrict__ scores,
                                                const float* __restrict__ btr,
                                                float2* __restrict__ MZ,
                                                float* __restrict__ bias) {
    int t = threadIdx.x;
    if (blockIdx.x == 16) {
        if (t < 256) {
            float s = 0.f;
#pragma unroll
            for (int h = 0; h < H_HEADS; ++h) s += btr[h * C_CH + t];
            bias[t] = s;
        }
        return;
    }
    __shared__ float red[17];
    int h = blockIdx.x;
    int wid = t >> 6, ln = t & 63;
    const float* sp = scores + (size_t)h * L_LEN;
    float v[16];
    float mx = -1e30f;
#pragma unroll
    for (int i = 0; i < 16; ++i) {
        v[i] = sp[i * 1024 + t];
        mx = fmaxf(mx, v[i]);
    }
    for (int o = 32; o > 0; o >>= 1) mx = fmaxf(mx, __shfl_xor(mx, o));
    if (ln == 0) red[wid] = mx;
    __syncthreads();
    if (t == 0) {
        float m2 = red[0];
        for (int i = 1; i < 16; ++i) m2 = fmaxf(m2, red[i]);
        red[16] = m2;
    }
    __syncthreads();
    float M = red[16];
    float s = 0.f;
#pragma unroll
    for (int i = 0; i < 16; ++i) s += __expf(v[i] - M);
    for (int o = 32; o > 0; o >>= 1) s += __shfl_xor(s, o);
    __syncthreads();
    if (ln == 0) red[wid] = s;
    __syncthreads();
    if (t == 0) {
        float Z = 0.f;
        for (int i = 0; i < 16; ++i) Z += red[i];
        float2 r; r.x = M; r.y = 1.0f / Z;
        MZ[h] = r;
    }
}

// GEMM: out[256][16384]. B panel LDS-resident; A streamed through 4 LDS buffers
// with counted vmcnt (T4) + raw barriers; focus via prologue LDS table.
// BM=128 BN=128 BK=64, 256 thr (4 waves 2x2), grid (128 n, 2 m) = 256 blocks.
#define BRES 65536
#define ATS  16384
#define FTAB (BRES + 4 * ATS)          // 131072; +8 KB table -> 139264 total

__global__ __launch_bounds__(256, 1) void k_gemm(const ushort_t* __restrict__ Ag,
                                                 const ushort_t* __restrict__ xb,
                                                 const float* __restrict__ scores,
                                                 const float2* __restrict__ MZ,
                                                 const float* __restrict__ bias,
                                                 float* __restrict__ out) {
    __shared__ char lds[FTAB + 8192];
    int t = threadIdx.x;
    int w = t >> 6, lane = t & 63;
    int m0 = blockIdx.y * 128, n0 = blockIdx.x * 128;
    int wr = w >> 1, wc = w & 1;
    int r = lane & 15, q = lane >> 4;

    // ---- prologue: B panel (linear gll16, swizzled content) ----
#pragma unroll
    for (int i = 0; i < 16; ++i) {
        int chunk = t + i * 256;
        int row = chunk >> 5, cb = (chunk & 31) * 16;
        gll16((const char*)xb + (size_t)(n0 + row) * 512 + cb, lds + chunk * 16);
    }
    // ---- focus table: ftab[h][nn] = exp(s - M_h) / Z_h  (2048 f32, 8 KB) ----
    {
        int idx = t * 8;
        int hh = idx >> 7, nn = idx & 127;
        float2 mz = MZ[hh];
        const float* sp = scores + (size_t)hh * L_LEN + n0 + nn;
        float* ft = (float*)(lds + FTAB);
#pragma unroll
        for (int e = 0; e < 8; ++e)
            ft[idx + e] = __expf(sp[e] - mz.x) * mz.y;
    }
    const f32x4 vzero = {0.f, 0.f, 0.f, 0.f};
    f32x4 oacc[4][4], hacc[4][4];
#pragma unroll
    for (int i = 0; i < 4; ++i)
#pragma unroll
        for (int j = 0; j < 4; ++j) { oacc[i][j] = vzero; hacc[i][j] = vzero; }

    __syncthreads();                       // full drain: B + ftab visible

    auto stageA = [&](int buf, int kt) {   // 4 x gll16 per thread
        const char* src = (const char*)Ag + (size_t)(m0 + (t >> 3)) * 8192 + kt * 128 + (t & 7) * 16;
        char* dst = lds + BRES + buf * ATS + t * 16;
#pragma unroll
        for (int j = 0; j < 4; ++j)
            gll16(src + (size_t)j * 32 * 8192, dst + j * 4096);
    };
    auto compute = [&](int buf) {
        char* Ab = lds + BRES + buf * ATS;
        __builtin_amdgcn_s_setprio(1);
#pragma unroll
        for (int kk = 0; kk < 2; ++kk) {
            bf16x8 a[4], bb[4];
#pragma unroll
            for (int i = 0; i < 4; ++i) {
                int ar = wr * 64 + i * 16 + r;
                a[i] = *(const bf16x8*)(Ab + ar * 128 + ((kk * 64 + q * 16) ^ ((ar & 7) << 4)));
            }
#pragma unroll
            for (int j = 0; j < 4; ++j) {
                int br = wc * 64 + j * 16 + r;
                bb[j] = *(const bf16x8*)(lds + br * 512 +
                          ((buf * 0 + kk * 64 + q * 16)));   // col computed below
            }
            (void)bb;
#pragma unroll
            for (int i = 0; i < 4; ++i)
#pragma unroll
                for (int j = 0; j < 4; ++j)
                    hacc[i][j] = __builtin_amdgcn_mfma_f32_16x16x32_bf16(a[i], bb[j], hacc[i][j], 0, 0, 0);
        }
        __builtin_amdgcn_s_setprio(0);
    };
    (void)compute;  // replaced by COMPUTE macro below (needs qq for B column)

#define COMPUTE(BUF, QQ)                                                          \
    {                                                                             \
        char* Ab = lds + BRES + (BUF) * ATS;                                      \
        __builtin_amdgcn_s_setprio(1);                                            \
        _Pragma("unroll")                                                         \
        for (int kk = 0; kk < 2; ++kk) {                                          \
            bf16x8 a[4], bb[4];                                                   \
            _Pragma("unroll")                                                     \
            for (int i = 0; i < 4; ++i) {                                         \
                int ar = wr * 64 + i * 16 + r;                                    \
                a[i] = *(const bf16x8*)(Ab + ar * 128 +                           \
                          ((kk * 64 + q * 16) ^ ((ar & 7) << 4)));                \
            }                                                                     \
            _Pragma("unroll")                                                     \
            for (int j = 0; j < 4; ++j) {                                         \
                int br = wc * 64 + j * 16 + r;                                    \
                bb[j] = *(const bf16x8*)(lds + br * 512 +                         \
                          (((QQ) * 128 + kk * 64 + q * 16) ^ ((br & 7) << 4)));   \
            }                                                                     \
            _Pragma("unroll")                                                     \
            for (int i = 0; i < 4; ++i)                                           \
                _Pragma("unroll")                                                 \
                for (int j = 0; j < 4; ++j)                                       \
                    hacc[i][j] = __builtin_amdgcn_mfma_f32_16x16x32_bf16(         \
                        a[i], bb[j], hacc[i][j], 0, 0, 0);                        \
        }                                                                         \
        __builtin_amdgcn_s_setprio(0);                                            \
    }

#define SCALE(H)                                                                  \
    {                                                                             \
        const float* ft = (const float*)(lds + FTAB) + (H) * 128;                 \
        float f[4];                                                               \
        _Pragma("unroll")                                                         \
        for (int j = 0; j < 4; ++j) f[j] = ft[wc * 64 + j * 16 + r];              \
        _Pragma("unroll")                                                         \
        for (int i = 0; i < 4; ++i)                                               \
            _Pragma("unroll")                                                     \
            for (int j = 0; j < 4; ++j) {                                         \
                oacc[i][j] += hacc[i][j] * f[j];                                  \
                hacc[i][j] = vzero;                                               \
            }                                                                     \
    }

    // warm the pipeline: stages 0..2 in flight (12 loads/thread)
    stageA(0, 0); stageA(1, 1); stageA(2, 2);

    for (int h = 0; h < 15; ++h) {
#pragma unroll
        for (int qq = 0; qq < 4; ++qq) {
            int kt = h * 4 + qq;
            asm volatile("s_waitcnt vmcnt(8)" ::: "memory");   // stage kt landed
            __builtin_amdgcn_s_barrier();
            stageA((kt + 3) & 3, kt + 3);                      // kt+3 <= 62
            COMPUTE(kt & 3, qq);
        }
        SCALE(h);
    }
    // h = 15 peeled (kt = 60..63)
    asm volatile("s_waitcnt vmcnt(8)" ::: "memory");
    __builtin_amdgcn_s_barrier();
    stageA(3, 63);
    COMPUTE(0, 0);
    asm volatile("s_waitcnt vmcnt(8)" ::: "memory");
    __builtin_amdgcn_s_barrier();
    COMPUTE(1, 1);
    asm volatile("s_waitcnt vmcnt(4)" ::: "memory");
    __builtin_amdgcn_s_barrier();
    COMPUTE(2, 2);
    asm volatile("s_waitcnt vmcnt(0)" ::: "memory");
    __builtin_amdgcn_s_barrier();
    COMPUTE(3, 3);
    SCALE(15);

#pragma unroll
    for (int i = 0; i < 4; ++i) {
        int mrow = m0 + wr * 64 + i * 16 + q * 4;
        float4 bv = *(const float4*)&bias[mrow];
        float bvr[4] = {bv.x, bv.y, bv.z, bv.w};
#pragma unroll
        for (int j = 0; j < 4; ++j) {
            int n = n0 + wc * 64 + j * 16 + r;
#pragma unroll
            for (int rr = 0; rr < 4; ++rr)
                out[(size_t)(mrow + rr) * L_LEN + n] = oacc[i][j][rr] + bvr[rr];
        }
    }
#undef COMPUTE
#undef SCALE
}

extern "C" void kernel_launch(void* const* d_in, const int* in_sizes, int n_in,
                              void* d_out, int out_size, void* d_ws, size_t ws_size,
                              hipStream_t stream) {
    const float* x   = (const float*)d_in[0];
    const float* wh  = (const float*)d_in[1];
    const float* wtr = (const float*)d_in[3];
    const float* btr = (const float*)d_in[4];
    float* out = (float*)d_out;
    char* ws = (char*)d_ws;

    ushort_t* Ag     = (ushort_t*)(ws);
    ushort_t* xb     = (ushort_t*)(ws + ((size_t)2 << 20));
    float*    scores = (float*)(ws + ((size_t)10 << 20));
    ushort_t* awf    = (ushort_t*)(ws + ((size_t)11 << 20));
    char*     sc     = ws + ((size_t)11 << 20) + (128 << 10);
    float2*   MZ     = (float2*)(sc);
    float*    bias   = (float*)(sc + 1024);

    k_transpose<<<dim3(256, 4), 256, 0, stream>>>(x, xb);
    k_aconv<<<dim3(512), 256, 0, stream>>>(wtr, Ag);
    k_wprep<<<dim3(240), 256, 0, stream>>>(wh, awf);
    k_convm<<<dim3(512), 128, 0, stream>>>(xb, awf, scores);
    k_stats<<<dim3(17), 1024, 0, stream>>>(scores, btr, MZ, bias);
    k_gemm<<<dim3(128, 2), 256, 0, stream>>>(Ag, xb, scores, MZ, bias, out);
}

// Round 6
// 122.945 us; speedup vs baseline: 2.2445x; 1.0630x over previous
//
#include <hip/hip_runtime.h>
#include <hip/hip_bf16.h>

#define L_LEN 16384
#define C_CH  256
#define H_HEADS 16
#define W_WIN 15

typedef __attribute__((ext_vector_type(8))) short bf16x8;
typedef __attribute__((ext_vector_type(4))) float f32x4;
typedef unsigned short ushort_t;

// ---------------- ws layout (bytes) ----------------
// Ag     : [256][4096] bf16, per-128B-window XOR-swizzled  @ 0      (2 MB)
// xb     : [16384][256] bf16, per-row XOR-swizzled         @ 2 MB   (8 MB)
// scores : [16][16384] f32 (raw conv out, no b_heads)      @ 10 MB  (1 MB)
// awf    : [15][8][64][8] bf16 A-fragments of w_heads      @ 11 MB  (120 KB)
// MZ     : [16] float2   @ 11M+128K
// bias   : [256] f32     @ +1024

__device__ __forceinline__ void gll16(const void* g, void* l) {
    __builtin_amdgcn_global_load_lds(
        (const __attribute__((address_space(1))) void*)g,
        (__attribute__((address_space(3))) void*)l, 16, 0, 0);
}

__device__ __forceinline__ ushort_t f2bf(float f) {
    __hip_bfloat16 b = __float2bfloat16(f);
    return *(ushort_t*)&b;
}

// Fused prep: blocks [0,1024) transpose x->xb_swz; [1024,1536) w_tr->Ag_swz;
// [1536,1776) w_heads->awf. All 256 thr.
__global__ __launch_bounds__(256) void k_prep(const float* __restrict__ x,
                                              const float* __restrict__ wtr,
                                              const float* __restrict__ wh,
                                              ushort_t* __restrict__ xb,
                                              ushort_t* __restrict__ Ag,
                                              ushort_t* __restrict__ awf) {
    int bid = blockIdx.x;
    int t = threadIdx.x;
    if (bid < 1024) {
        // x [256][16384] f32 -> xb [16384][256] bf16, row-swizzled
        __shared__ float tile[64][65];
        int l0 = (bid & 255) * 64;
        int c0 = (bid >> 8) * 64;
#pragma unroll
        for (int r = 0; r < 16; ++r) {
            int c = r * 4 + (t >> 6);
            int l = t & 63;
            tile[c][l] = x[(size_t)(c0 + c) * L_LEN + l0 + l];
        }
        __syncthreads();
        int l = t >> 2;
        int cq = (t & 3) * 16;
        ushort_t tmp[16];
#pragma unroll
        for (int i = 0; i < 16; ++i) tmp[i] = f2bf(tile[cq + i][l]);
        char* rowp = (char*)(xb + (size_t)(l0 + l) * C_CH);
        int swz = (l & 7) << 4;
        int b0 = (c0 + cq) * 2;
        *(uint4*)(rowp + (b0 ^ swz)) = *(uint4*)&tmp[0];
        *(uint4*)(rowp + ((b0 + 16) ^ swz)) = *(uint4*)&tmp[8];
    } else if (bid < 1536) {
        // w_tr [16][256][256] f32 -> Ag swizzled bf16
        int tid = (bid - 1024) * 256 + t;       // 131072 chunks of 16 B
        size_t D = (size_t)tid * 16;
        int m = (int)(D >> 13);
        int inner = (int)(D & 8191);
        int kt = inner >> 7, wb = inner & 127;
        int ob = kt * 128 + (wb ^ ((m & 7) << 4));
        int k0 = ob >> 1;
        int h = k0 >> 8, c = k0 & 255;
        const float* src = wtr + ((size_t)h * C_CH + m) * C_CH + c;
        ushort_t tmp[8];
#pragma unroll
        for (int i = 0; i < 8; ++i) tmp[i] = f2bf(src[i]);
        *(uint4*)((char*)Ag + D) = *(uint4*)tmp;
    } else {
        // w_heads [16][256][15] f32 -> awf MFMA A-fragment order
        int tid = (bid - 1536) * 256 + t;       // 61440
        int e = tid & 7;
        int lane = (tid >> 3) & 63;
        int ktw = tid >> 9;
        int w = ktw >> 3, kt = ktw & 7;
        int h = lane & 15;
        int c = kt * 32 + (lane >> 4) * 8 + e;
        awf[tid] = f2bf(wh[((size_t)h * C_CH + c) * W_WIN + w]);
    }
}

// conv via MFMA -> scores[16][L]. grid 512 (l-tile 32), 128 thr (2 waves).
__global__ __launch_bounds__(128) void k_convm(const ushort_t* __restrict__ xb,
                                               const ushort_t* __restrict__ awf,
                                               float* __restrict__ scores) {
    __shared__ char xs[48 * 512];
    int t = threadIdx.x;
    int n0 = blockIdx.x * 32;
#pragma unroll
    for (int i = 0; i < 12; ++i) {
        int chunk = t + i * 128;
        int rr = chunk >> 5;
        int cb = (chunk & 31) * 16;
        int l = n0 - 8 + rr;
        int lc = l < 0 ? 0 : (l >= L_LEN ? L_LEN - 1 : l);
        gll16((const char*)xb + (size_t)lc * 512 + cb, xs + chunk * 16);
    }
    __syncthreads();
    if (n0 == 0 || n0 == L_LEN - 32) {
        int rbase = (n0 == 0) ? 0 : 40;
        uint4 z = {0u, 0u, 0u, 0u};
#pragma unroll
        for (int i = 0; i < 2; ++i) {
            int ch = t + i * 128;
            *(uint4*)(xs + rbase * 512 + ch * 16) = z;
        }
        __syncthreads();
    }
    int wv = t >> 6, lane = t & 63;
    int r = lane & 15, q = lane >> 4;
    const f32x4 vzero = {0.f, 0.f, 0.f, 0.f};
    f32x4 acc[4] = {vzero, vzero, vzero, vzero};
    for (int w = 0; w < 15; ++w) {
        int rr = wv * 16 + r + w + 1;
        const char* rowp = &xs[rr * 512];
        int sw = (rr & 7) << 4;
#pragma unroll
        for (int kt = 0; kt < 8; ++kt) {
            bf16x8 a = *(const bf16x8*)(awf + (size_t)(((w * 8 + kt) * 64 + lane) * 8));
            bf16x8 b = *(const bf16x8*)(rowp + ((kt * 64 + q * 16) ^ sw));
            acc[kt & 3] = __builtin_amdgcn_mfma_f32_16x16x32_bf16(a, b, acc[kt & 3], 0, 0, 0);
        }
    }
    f32x4 s = acc[0] + acc[1] + acc[2] + acc[3];
    int nb = n0 + wv * 16;
#pragma unroll
    for (int e = 0; e < 4; ++e)
        scores[(size_t)(q * 4 + e) * L_LEN + nb + r] = s[e];
}

// softmax stats (M,1/Z) per head + head-summed bias. grid 17 x 1024.
__global__ __launch_bounds__(1024) void k_stats(const float* __restrict__ scores,
                                                const float* __restrict__ btr,
                                                float2* __restrict__ MZ,
                                                float* __restrict__ bias) {
    int t = threadIdx.x;
    if (blockIdx.x == 16) {
        if (t < 256) {
            float s = 0.f;
#pragma unroll
            for (int h = 0; h < H_HEADS; ++h) s += btr[h * C_CH + t];
            bias[t] = s;
        }
        return;
    }
    __shared__ float red[17];
    int h = blockIdx.x;
    int wid = t >> 6, ln = t & 63;
    const float* sp = scores + (size_t)h * L_LEN;
    float v[16];
    float mx = -1e30f;
#pragma unroll
    for (int i = 0; i < 16; ++i) {
        v[i] = sp[i * 1024 + t];
        mx = fmaxf(mx, v[i]);
    }
    for (int o = 32; o > 0; o >>= 1) mx = fmaxf(mx, __shfl_xor(mx, o));
    if (ln == 0) red[wid] = mx;
    __syncthreads();
    if (t == 0) {
        float m2 = red[0];
        for (int i = 1; i < 16; ++i) m2 = fmaxf(m2, red[i]);
        red[16] = m2;
    }
    __syncthreads();
    float M = red[16];
    float s = 0.f;
#pragma unroll
    for (int i = 0; i < 16; ++i) s += __expf(v[i] - M);
    for (int o = 32; o > 0; o >>= 1) s += __shfl_xor(s, o);
    __syncthreads();
    if (ln == 0) red[wid] = s;
    __syncthreads();
    if (t == 0) {
        float Z = 0.f;
        for (int i = 0; i < 16; ++i) Z += red[i];
        float2 r; r.x = M; r.y = 1.0f / Z;
        MZ[h] = r;
    }
}

// GEMM: out[256][16384]. 512 thr / 8 waves (2 waves/SIMD for TLP).
// B panel (64 KB) LDS-resident; A streamed through 4 buffers, counted vmcnt.
// BM=128 BN=128 BK=64; wave grid 2m x 4n, wave tile 64x32. grid (128 n, 2 m).
#define BRES 65536
#define ATS  16384
#define FTAB (BRES + 4 * ATS)          // 131072; +8 KB ftab -> 139264 total

__global__ __launch_bounds__(512, 1) void k_gemm(const ushort_t* __restrict__ Ag,
                                                 const ushort_t* __restrict__ xb,
                                                 const float* __restrict__ scores,
                                                 const float2* __restrict__ MZ,
                                                 const float* __restrict__ bias,
                                                 float* __restrict__ out) {
    __shared__ char lds[FTAB + 8192];
    int t = threadIdx.x;
    int w = t >> 6, lane = t & 63;
    int m0 = blockIdx.y * 128, n0 = blockIdx.x * 128;
    int wr = w >> 2, wc = w & 3;
    int r = lane & 15, q = lane >> 4;

    // ---- prologue: B panel (4096 x 16B chunks, 8/thread, linear gll16) ----
#pragma unroll
    for (int i = 0; i < 8; ++i) {
        int chunk = t + i * 512;
        int row = chunk >> 5, cb = (chunk & 31) * 16;
        gll16((const char*)xb + (size_t)(n0 + row) * 512 + cb, lds + chunk * 16);
    }
    // ---- focus table: ftab[h][nn] = exp(s - M_h)/Z_h (2048 f32, 4/thread) ----
    {
        int idx = t * 4;
        int hh = idx >> 7, nn = idx & 127;
        float2 mz = MZ[hh];
        const float* sp = scores + (size_t)hh * L_LEN + n0 + nn;
        float* ft = (float*)(lds + FTAB);
#pragma unroll
        for (int e = 0; e < 4; ++e)
            ft[idx + e] = __expf(sp[e] - mz.x) * mz.y;
    }
    const f32x4 vzero = {0.f, 0.f, 0.f, 0.f};
    f32x4 oacc[4][2], hacc[4][2];
#pragma unroll
    for (int i = 0; i < 4; ++i)
#pragma unroll
        for (int j = 0; j < 2; ++j) { oacc[i][j] = vzero; hacc[i][j] = vzero; }

    __syncthreads();                       // drains B + ftab (vmcnt 0 here)

    auto stageA = [&](int buf, int kt) {   // 2 x gll16 per thread (16 KB total)
        const char* src = (const char*)Ag + (size_t)(m0 + (t >> 3)) * 8192 + kt * 128 + (t & 7) * 16;
        char* dst = lds + BRES + buf * ATS + t * 16;
#pragma unroll
        for (int j = 0; j < 2; ++j)
            gll16(src + (size_t)j * 64 * 8192, dst + j * 8192);
    };

#define COMPUTE(BUF, QQ)                                                          \
    {                                                                             \
        char* Ab = lds + BRES + (BUF) * ATS;                                      \
        __builtin_amdgcn_s_setprio(1);                                            \
        _Pragma("unroll")                                                         \
        for (int kk = 0; kk < 2; ++kk) {                                          \
            bf16x8 a[4], bb[2];                                                   \
            _Pragma("unroll")                                                     \
            for (int i = 0; i < 4; ++i) {                                         \
                int ar = wr * 64 + i * 16 + r;                                    \
                a[i] = *(const bf16x8*)(Ab + ar * 128 +                           \
                          ((kk * 64 + q * 16) ^ ((ar & 7) << 4)));                \
            }                                                                     \
            _Pragma("unroll")                                                     \
            for (int j = 0; j < 2; ++j) {                                         \
                int br = wc * 32 + j * 16 + r;                                    \
                bb[j] = *(const bf16x8*)(lds + br * 512 +                         \
                          (((QQ) * 128 + kk * 64 + q * 16) ^ ((br & 7) << 4)));   \
            }                                                                     \
            _Pragma("unroll")                                                     \
            for (int i = 0; i < 4; ++i)                                           \
                _Pragma("unroll")                                                 \
                for (int j = 0; j < 2; ++j)                                       \
                    hacc[i][j] = __builtin_amdgcn_mfma_f32_16x16x32_bf16(         \
                        a[i], bb[j], hacc[i][j], 0, 0, 0);                        \
        }                                                                         \
        __builtin_amdgcn_s_setprio(0);                                            \
    }

#define SCALE(H)                                                                  \
    {                                                                             \
        const float* ft = (const float*)(lds + FTAB) + (H) * 128;                 \
        float f[2];                                                               \
        _Pragma("unroll")                                                         \
        for (int j = 0; j < 2; ++j) f[j] = ft[wc * 32 + j * 16 + r];              \
        _Pragma("unroll")                                                         \
        for (int i = 0; i < 4; ++i)                                               \
            _Pragma("unroll")                                                     \
            for (int j = 0; j < 2; ++j) {                                         \
                oacc[i][j] += hacc[i][j] * f[j];                                  \
                hacc[i][j] = vzero;                                               \
            }                                                                     \
    }

    // warm pipeline: stages 0..2 in flight (6 loads/wave outstanding)
    stageA(0, 0); stageA(1, 1); stageA(2, 2);

    for (int h = 0; h < 15; ++h) {
#pragma unroll
        for (int qq = 0; qq < 4; ++qq) {
            int kt = h * 4 + qq;
            asm volatile("s_waitcnt vmcnt(4)" ::: "memory");   // stage kt landed
            __builtin_amdgcn_s_barrier();
            stageA((kt + 3) & 3, kt + 3);                      // kt+3 <= 62
            COMPUTE(kt & 3, qq);
        }
        SCALE(h);
    }
    // h = 15 peeled (kt = 60..63)
    asm volatile("s_waitcnt vmcnt(4)" ::: "memory");
    __builtin_amdgcn_s_barrier();
    stageA(3, 63);
    COMPUTE(0, 0);
    asm volatile("s_waitcnt vmcnt(4)" ::: "memory");
    __builtin_amdgcn_s_barrier();
    COMPUTE(1, 1);
    asm volatile("s_waitcnt vmcnt(2)" ::: "memory");
    __builtin_amdgcn_s_barrier();
    COMPUTE(2, 2);
    asm volatile("s_waitcnt vmcnt(0)" ::: "memory");
    __builtin_amdgcn_s_barrier();
    COMPUTE(3, 3);
    SCALE(15);

#pragma unroll
    for (int i = 0; i < 4; ++i) {
        int mrow = m0 + wr * 64 + i * 16 + q * 4;
        float4 bv = *(const float4*)&bias[mrow];
        float bvr[4] = {bv.x, bv.y, bv.z, bv.w};
#pragma unroll
        for (int j = 0; j < 2; ++j) {
            int n = n0 + wc * 32 + j * 16 + r;
#pragma unroll
            for (int rr = 0; rr < 4; ++rr)
                out[(size_t)(mrow + rr) * L_LEN + n] = oacc[i][j][rr] + bvr[rr];
        }
    }
#undef COMPUTE
#undef SCALE
}

extern "C" void kernel_launch(void* const* d_in, const int* in_sizes, int n_in,
                              void* d_out, int out_size, void* d_ws, size_t ws_size,
                              hipStream_t stream) {
    const float* x   = (const float*)d_in[0];
    const float* wh  = (const float*)d_in[1];
    const float* wtr = (const float*)d_in[3];
    const float* btr = (const float*)d_in[4];
    float* out = (float*)d_out;
    char* ws = (char*)d_ws;

    ushort_t* Ag     = (ushort_t*)(ws);
    ushort_t* xb     = (ushort_t*)(ws + ((size_t)2 << 20));
    float*    scores = (float*)(ws + ((size_t)10 << 20));
    ushort_t* awf    = (ushort_t*)(ws + ((size_t)11 << 20));
    char*     sc     = ws + ((size_t)11 << 20) + (128 << 10);
    float2*   MZ     = (float2*)(sc);
    float*    bias   = (float*)(sc + 1024);

    k_prep<<<dim3(1776), 256, 0, stream>>>(x, wtr, wh, xb, Ag, awf);
    k_convm<<<dim3(512), 128, 0, stream>>>(xb, awf, scores);
    k_stats<<<dim3(17), 1024, 0, stream>>>(scores, btr, MZ, bias);
    k_gemm<<<dim3(128, 2), 512, 0, stream>>>(Ag, xb, scores, MZ, bias, out);
}

// Round 7
// 121.327 us; speedup vs baseline: 2.2745x; 1.0133x over previous
//
#include <hip/hip_runtime.h>
#include <hip/hip_bf16.h>

#define L_LEN 16384
#define C_CH  256
#define H_HEADS 16
#define W_WIN 15

typedef __attribute__((ext_vector_type(8))) short bf16x8;
typedef __attribute__((ext_vector_type(4))) float f32x4;
typedef unsigned short ushort_t;

// ---------------- ws layout (bytes) ----------------
// Ag     : [256][4096] bf16, per-128B-window XOR-swizzled  @ 0      (2 MB)
// xb     : [16384][256] bf16, per-row XOR-swizzled         @ 2 MB   (8 MB)
// scores : [16][16384] f32 (raw conv out, no b_heads)      @ 10 MB  (1 MB)
// awf    : [15][8][64][8] bf16 A-fragments of w_heads      @ 11 MB  (120 KB)
// MZ     : [16] float2   @ 11M+128K
// bias   : [256] f32     @ +1024

__device__ __forceinline__ void gll16(const void* g, void* l) {
    __builtin_amdgcn_global_load_lds(
        (const __attribute__((address_space(1))) void*)g,
        (__attribute__((address_space(3))) void*)l, 16, 0, 0);
}

__device__ __forceinline__ ushort_t f2bf(float f) {
    __hip_bfloat16 b = __float2bfloat16(f);
    return *(ushort_t*)&b;
}

// Fused prep: blocks [0,1024) transpose x->xb_swz; [1024,1536) w_tr->Ag_swz;
// [1536,1776) w_heads->awf. All 256 thr.
__global__ __launch_bounds__(256) void k_prep(const float* __restrict__ x,
                                              const float* __restrict__ wtr,
                                              const float* __restrict__ wh,
                                              ushort_t* __restrict__ xb,
                                              ushort_t* __restrict__ Ag,
                                              ushort_t* __restrict__ awf) {
    int bid = blockIdx.x;
    int t = threadIdx.x;
    if (bid < 1024) {
        __shared__ float tile[64][65];
        int l0 = (bid & 255) * 64;
        int c0 = (bid >> 8) * 64;
#pragma unroll
        for (int r = 0; r < 16; ++r) {
            int c = r * 4 + (t >> 6);
            int l = t & 63;
            tile[c][l] = x[(size_t)(c0 + c) * L_LEN + l0 + l];
        }
        __syncthreads();
        int l = t >> 2;
        int cq = (t & 3) * 16;
        ushort_t tmp[16];
#pragma unroll
        for (int i = 0; i < 16; ++i) tmp[i] = f2bf(tile[cq + i][l]);
        char* rowp = (char*)(xb + (size_t)(l0 + l) * C_CH);
        int swz = (l & 7) << 4;
        int b0 = (c0 + cq) * 2;
        *(uint4*)(rowp + (b0 ^ swz)) = *(uint4*)&tmp[0];
        *(uint4*)(rowp + ((b0 + 16) ^ swz)) = *(uint4*)&tmp[8];
    } else if (bid < 1536) {
        int tid = (bid - 1024) * 256 + t;
        size_t D = (size_t)tid * 16;
        int m = (int)(D >> 13);
        int inner = (int)(D & 8191);
        int kt = inner >> 7, wb = inner & 127;
        int ob = kt * 128 + (wb ^ ((m & 7) << 4));
        int k0 = ob >> 1;
        int h = k0 >> 8, c = k0 & 255;
        const float* src = wtr + ((size_t)h * C_CH + m) * C_CH + c;
        ushort_t tmp[8];
#pragma unroll
        for (int i = 0; i < 8; ++i) tmp[i] = f2bf(src[i]);
        *(uint4*)((char*)Ag + D) = *(uint4*)tmp;
    } else {
        int tid = (bid - 1536) * 256 + t;
        int e = tid & 7;
        int lane = (tid >> 3) & 63;
        int ktw = tid >> 9;
        int w = ktw >> 3, kt = ktw & 7;
        int h = lane & 15;
        int c = kt * 32 + (lane >> 4) * 8 + e;
        awf[tid] = f2bf(wh[((size_t)h * C_CH + c) * W_WIN + w]);
    }
}

// conv via MFMA -> scores[16][L]. grid 512 (l-tile 32), 128 thr (2 waves).
__global__ __launch_bounds__(128) void k_convm(const ushort_t* __restrict__ xb,
                                               const ushort_t* __restrict__ awf,
                                               float* __restrict__ scores) {
    __shared__ char xs[48 * 512];
    int t = threadIdx.x;
    int n0 = blockIdx.x * 32;
#pragma unroll
    for (int i = 0; i < 12; ++i) {
        int chunk = t + i * 128;
        int rr = chunk >> 5;
        int cb = (chunk & 31) * 16;
        int l = n0 - 8 + rr;
        int lc = l < 0 ? 0 : (l >= L_LEN ? L_LEN - 1 : l);
        gll16((const char*)xb + (size_t)lc * 512 + cb, xs + chunk * 16);
    }
    __syncthreads();
    if (n0 == 0 || n0 == L_LEN - 32) {
        int rbase = (n0 == 0) ? 0 : 40;
        uint4 z = {0u, 0u, 0u, 0u};
#pragma unroll
        for (int i = 0; i < 2; ++i) {
            int ch = t + i * 128;
            *(uint4*)(xs + rbase * 512 + ch * 16) = z;
        }
        __syncthreads();
    }
    int wv = t >> 6, lane = t & 63;
    int r = lane & 15, q = lane >> 4;
    const f32x4 vzero = {0.f, 0.f, 0.f, 0.f};
    f32x4 acc[4] = {vzero, vzero, vzero, vzero};
    for (int w = 0; w < 15; ++w) {
        int rr = wv * 16 + r + w + 1;
        const char* rowp = &xs[rr * 512];
        int sw = (rr & 7) << 4;
#pragma unroll
        for (int kt = 0; kt < 8; ++kt) {
            bf16x8 a = *(const bf16x8*)(awf + (size_t)(((w * 8 + kt) * 64 + lane) * 8));
            bf16x8 b = *(const bf16x8*)(rowp + ((kt * 64 + q * 16) ^ sw));
            acc[kt & 3] = __builtin_amdgcn_mfma_f32_16x16x32_bf16(a, b, acc[kt & 3], 0, 0, 0);
        }
    }
    f32x4 s = acc[0] + acc[1] + acc[2] + acc[3];
    int nb = n0 + wv * 16;
#pragma unroll
    for (int e = 0; e < 4; ++e)
        scores[(size_t)(q * 4 + e) * L_LEN + nb + r] = s[e];
}

// softmax stats (M,1/Z) per head + head-summed bias. grid 17 x 1024.
__global__ __launch_bounds__(1024) void k_stats(const float* __restrict__ scores,
                                                const float* __restrict__ btr,
                                                float2* __restrict__ MZ,
                                                float* __restrict__ bias) {
    int t = threadIdx.x;
    if (blockIdx.x == 16) {
        if (t < 256) {
            float s = 0.f;
#pragma unroll
            for (int h = 0; h < H_HEADS; ++h) s += btr[h * C_CH + t];
            bias[t] = s;
        }
        return;
    }
    __shared__ float red[17];
    int h = blockIdx.x;
    int wid = t >> 6, ln = t & 63;
    const float* sp = scores + (size_t)h * L_LEN;
    float v[16];
    float mx = -1e30f;
#pragma unroll
    for (int i = 0; i < 16; ++i) {
        v[i] = sp[i * 1024 + t];
        mx = fmaxf(mx, v[i]);
    }
    for (int o = 32; o > 0; o >>= 1) mx = fmaxf(mx, __shfl_xor(mx, o));
    if (ln == 0) red[wid] = mx;
    __syncthreads();
    if (t == 0) {
        float m2 = red[0];
        for (int i = 1; i < 16; ++i) m2 = fmaxf(m2, red[i]);
        red[16] = m2;
    }
    __syncthreads();
    float M = red[16];
    float s = 0.f;
#pragma unroll
    for (int i = 0; i < 16; ++i) s += __expf(v[i] - M);
    for (int o = 32; o > 0; o >>= 1) s += __shfl_xor(s, o);
    __syncthreads();
    if (ln == 0) red[wid] = s;
    __syncthreads();
    if (t == 0) {
        float Z = 0.f;
        for (int i = 0; i < 16; ++i) Z += red[i];
        float2 r; r.x = M; r.y = 1.0f / Z;
        MZ[h] = r;
    }
}

// GEMM: out[256][16384]. 512 thr / 8 waves. B panel LDS-resident; B fragments
// register-cached across heads (loaded h=0, reused h=1..15 -> B LDS reads /16).
// A streamed through 4 buffers, counted vmcnt. BM=128 BN=128 BK=64.
#define BRES 65536
#define ATS  16384
#define FTAB (BRES + 4 * ATS)          // 131072; +8 KB ftab -> 139264 total

__global__ __launch_bounds__(512, 1) void k_gemm(const ushort_t* __restrict__ Ag,
                                                 const ushort_t* __restrict__ xb,
                                                 const float* __restrict__ scores,
                                                 const float2* __restrict__ MZ,
                                                 const float* __restrict__ bias,
                                                 float* __restrict__ out) {
    __shared__ char lds[FTAB + 8192];
    int t = threadIdx.x;
    int w = t >> 6, lane = t & 63;
    int m0 = blockIdx.y * 128, n0 = blockIdx.x * 128;
    int wr = w >> 2, wc = w & 3;
    int r = lane & 15, q = lane >> 4;
    int swz = (r & 7) << 4;             // both A and B row-swizzles reduce to this

    // ---- prologue: B panel (4096 x 16B chunks, 8/thread, linear gll16) ----
#pragma unroll
    for (int i = 0; i < 8; ++i) {
        int chunk = t + i * 512;
        int row = chunk >> 5, cb = (chunk & 31) * 16;
        gll16((const char*)xb + (size_t)(n0 + row) * 512 + cb, lds + chunk * 16);
    }
    // ---- focus table: ftab[h][nn] = exp(s - M_h)/Z_h (2048 f32, 4/thread) ----
    {
        int idx = t * 4;
        int hh = idx >> 7, nn = idx & 127;
        float2 mz = MZ[hh];
        const float* sp = scores + (size_t)hh * L_LEN + n0 + nn;
        float* ft = (float*)(lds + FTAB);
#pragma unroll
        for (int e = 0; e < 4; ++e)
            ft[idx + e] = __expf(sp[e] - mz.x) * mz.y;
    }
    const f32x4 vzero = {0.f, 0.f, 0.f, 0.f};
    f32x4 oacc[4][2], hacc[4][2];
#pragma unroll
    for (int i = 0; i < 4; ++i)
#pragma unroll
        for (int j = 0; j < 2; ++j) { oacc[i][j] = vzero; hacc[i][j] = vzero; }

    // B fragment register cache: head-invariant (c = QQ*64 + KK*32 + q*8 + e)
    bf16x8 br00_0, br00_1, br01_0, br01_1, br10_0, br10_1, br11_0, br11_1,
           br20_0, br20_1, br21_0, br21_1, br30_0, br30_1, br31_0, br31_1;

    __syncthreads();                       // drains B + ftab (vmcnt 0 here)

    auto stageA = [&](int buf, int kt) {   // 2 x gll16 per thread (16 KB total)
        const char* src = (const char*)Ag + (size_t)(m0 + (t >> 3)) * 8192 + kt * 128 + (t & 7) * 16;
        char* dst = lds + BRES + buf * ATS + t * 16;
#pragma unroll
        for (int j = 0; j < 2; ++j)
            gll16(src + (size_t)j * 64 * 8192, dst + j * 8192);
    };

#define BRN(QQ, KK, J) br##QQ##KK##_##J
#define LDB(QQ, KK, J)                                                            \
    BRN(QQ, KK, J) = *(const bf16x8*)(lds + (wc * 32 + (J) * 16 + r) * 512 +      \
                          (((QQ) * 128 + (KK) * 64 + q * 16) ^ swz))
#define LDA_(Ab, I, KK)                                                           \
    (*(const bf16x8*)((Ab) + (wr * 64 + (I) * 16 + r) * 128 +                     \
                      (((KK) * 64 + q * 16) ^ swz)))
#define CK(Ab, KK, B0, B1)                                                        \
    {                                                                             \
        bf16x8 a0 = LDA_(Ab, 0, KK), a1 = LDA_(Ab, 1, KK),                        \
               a2 = LDA_(Ab, 2, KK), a3 = LDA_(Ab, 3, KK);                        \
        hacc[0][0] = __builtin_amdgcn_mfma_f32_16x16x32_bf16(a0, B0, hacc[0][0], 0, 0, 0); \
        hacc[0][1] = __builtin_amdgcn_mfma_f32_16x16x32_bf16(a0, B1, hacc[0][1], 0, 0, 0); \
        hacc[1][0] = __builtin_amdgcn_mfma_f32_16x16x32_bf16(a1, B0, hacc[1][0], 0, 0, 0); \
        hacc[1][1] = __builtin_amdgcn_mfma_f32_16x16x32_bf16(a1, B1, hacc[1][1], 0, 0, 0); \
        hacc[2][0] = __builtin_amdgcn_mfma_f32_16x16x32_bf16(a2, B0, hacc[2][0], 0, 0, 0); \
        hacc[2][1] = __builtin_amdgcn_mfma_f32_16x16x32_bf16(a2, B1, hacc[2][1], 0, 0, 0); \
        hacc[3][0] = __builtin_amdgcn_mfma_f32_16x16x32_bf16(a3, B0, hacc[3][0], 0, 0, 0); \
        hacc[3][1] = __builtin_amdgcn_mfma_f32_16x16x32_bf16(a3, B1, hacc[3][1], 0, 0, 0); \
    }
#define COMPUTE_LD(BUF, QQ)                                                       \
    {                                                                             \
        char* Ab = lds + BRES + (BUF) * ATS;                                      \
        __builtin_amdgcn_s_setprio(1);                                            \
        LDB(QQ, 0, 0); LDB(QQ, 0, 1);                                             \
        CK(Ab, 0, BRN(QQ, 0, 0), BRN(QQ, 0, 1));                                  \
        LDB(QQ, 1, 0); LDB(QQ, 1, 1);                                             \
        CK(Ab, 1, BRN(QQ, 1, 0), BRN(QQ, 1, 1));                                  \
        __builtin_amdgcn_s_setprio(0);                                            \
    }
#define COMPUTE_RE(BUF, QQ)                                                       \
    {                                                                             \
        char* Ab = lds + BRES + (BUF) * ATS;                                      \
        __builtin_amdgcn_s_setprio(1);                                            \
        CK(Ab, 0, BRN(QQ, 0, 0), BRN(QQ, 0, 1));                                  \
        CK(Ab, 1, BRN(QQ, 1, 0), BRN(QQ, 1, 1));                                  \
        __builtin_amdgcn_s_setprio(0);                                            \
    }
#define SCALE(H)                                                                  \
    {                                                                             \
        const float* ft = (const float*)(lds + FTAB) + (H) * 128;                 \
        float f0 = ft[wc * 32 + r], f1 = ft[wc * 32 + 16 + r];                    \
        _Pragma("unroll")                                                         \
        for (int i = 0; i < 4; ++i) {                                             \
            oacc[i][0] += hacc[i][0] * f0;                                        \
            oacc[i][1] += hacc[i][1] * f1;                                        \
            hacc[i][0] = vzero;                                                   \
            hacc[i][1] = vzero;                                                   \
        }                                                                         \
    }
#define PHASE(SBUF, SKT, CBUF, QQ, CMP)                                           \
    asm volatile("s_waitcnt vmcnt(4)" ::: "memory");                              \
    __builtin_amdgcn_s_barrier();                                                 \
    stageA((SBUF), (SKT));                                                        \
    CMP((CBUF), QQ);

    // warm pipeline: stages 0..2 in flight
    stageA(0, 0); stageA(1, 1); stageA(2, 2);

    // h = 0: load B frags to registers while computing
    PHASE(3, 3, 0, 0, COMPUTE_LD)
    PHASE(0, 4, 1, 1, COMPUTE_LD)
    PHASE(1, 5, 2, 2, COMPUTE_LD)
    PHASE(2, 6, 3, 3, COMPUTE_LD)
    SCALE(0);

    for (int h = 1; h < 15; ++h) {
        int k4 = h * 4;
        PHASE(3, k4 + 3, 0, 0, COMPUTE_RE)
        PHASE(0, k4 + 4, 1, 1, COMPUTE_RE)
        PHASE(1, k4 + 5, 2, 2, COMPUTE_RE)
        PHASE(2, k4 + 6, 3, 3, COMPUTE_RE)
        SCALE(h);
    }

    // h = 15 peeled (kt = 60..63)
    asm volatile("s_waitcnt vmcnt(4)" ::: "memory");
    __builtin_amdgcn_s_barrier();
    stageA(3, 63);
    COMPUTE_RE(0, 0);
    asm volatile("s_waitcnt vmcnt(4)" ::: "memory");
    __builtin_amdgcn_s_barrier();
    COMPUTE_RE(1, 1);
    asm volatile("s_waitcnt vmcnt(2)" ::: "memory");
    __builtin_amdgcn_s_barrier();
    COMPUTE_RE(2, 2);
    asm volatile("s_waitcnt vmcnt(0)" ::: "memory");
    __builtin_amdgcn_s_barrier();
    COMPUTE_RE(3, 3);
    SCALE(15);

#pragma unroll
    for (int i = 0; i < 4; ++i) {
        int mrow = m0 + wr * 64 + i * 16 + q * 4;
        float4 bv = *(const float4*)&bias[mrow];
        float bvr[4] = {bv.x, bv.y, bv.z, bv.w};
#pragma unroll
        for (int j = 0; j < 2; ++j) {
            int n = n0 + wc * 32 + j * 16 + r;
#pragma unroll
            for (int rr = 0; rr < 4; ++rr)
                out[(size_t)(mrow + rr) * L_LEN + n] = oacc[i][j][rr] + bvr[rr];
        }
    }
#undef PHASE
#undef SCALE
#undef COMPUTE_RE
#undef COMPUTE_LD
#undef CK
#undef LDA_
#undef LDB
#undef BRN
}

extern "C" void kernel_launch(void* const* d_in, const int* in_sizes, int n_in,
                              void* d_out, int out_size, void* d_ws, size_t ws_size,
                              hipStream_t stream) {
    const float* x   = (const float*)d_in[0];
    const float* wh  = (const float*)d_in[1];
    const float* wtr = (const float*)d_in[3];
    const float* btr = (const float*)d_in[4];
    float* out = (float*)d_out;
    char* ws = (char*)d_ws;

    ushort_t* Ag     = (ushort_t*)(ws);
    ushort_t* xb     = (ushort_t*)(ws + ((size_t)2 << 20));
    float*    scores = (float*)(ws + ((size_t)10 << 20));
    ushort_t* awf    = (ushort_t*)(ws + ((size_t)11 << 20));
    char*     sc     = ws + ((size_t)11 << 20) + (128 << 10);
    float2*   MZ     = (float2*)(sc);
    float*    bias   = (float*)(sc + 1024);

    k_prep<<<dim3(1776), 256, 0, stream>>>(x, wtr, wh, xb, Ag, awf);
    k_convm<<<dim3(512), 128, 0, stream>>>(xb, awf, scores);
    k_stats<<<dim3(17), 1024, 0, stream>>>(scores, btr, MZ, bias);
    k_gemm<<<dim3(128, 2), 512, 0, stream>>>(Ag, xb, scores, MZ, bias, out);
}